// Round 2
// baseline (103.802 us; speedup 1.0000x reference)
//
#include <hip/hip_runtime.h>
#include <hip/hip_bf16.h>
#include <math.h>

#define NB 16      // batch
#define LAT 128
#define HID 256
#define NN 256     // nodes
#define NH 4       // heads
#define JT 8       // dst-tile per gat block

__device__ __forceinline__ float lrelu02(float x){ return x > 0.f ? x : 0.2f*x; }
__device__ __forceinline__ float eluf(float x){ return x > 0.f ? x : expm1f(x); }

// ---------------- K1: h2 = relu(relu(x@W0+b0)@W1+b1)  [16,256] ----------------
__global__ __launch_bounds__(256) void k_mlp12(const float* __restrict__ x,
    const float* __restrict__ W0, const float* __restrict__ b0,
    const float* __restrict__ W1, const float* __restrict__ b1,
    float* __restrict__ h2)
{
    __shared__ float xs[LAT];
    __shared__ float h1s[HID];
    int b = blockIdx.x, t = threadIdx.x;
    if (t < LAT) xs[t] = x[b*LAT + t];
    __syncthreads();
    float acc = b0[t];
    for (int k = 0; k < LAT; ++k) acc = fmaf(xs[k], W0[k*HID + t], acc);
    h1s[t] = fmaxf(acc, 0.f);
    __syncthreads();
    float acc2 = b1[t];
    for (int k = 0; k < HID; ++k) acc2 = fmaf(h1s[k], W1[k*HID + t], acc2);
    h2[b*HID + t] = fmaxf(acc2, 0.f);
}

// ---------------- K2: fused h3 = h2@W2+b2 (one node/block) then gfeat = h3@Wg,
//                  a_s/a_d head reductions. gfeat lives in d_out (4MB). --------
__global__ __launch_bounds__(256) void k_mlp3g(
    const float* __restrict__ h2, const float* __restrict__ W2,
    const float* __restrict__ b2, const float* __restrict__ Wg,
    const float* __restrict__ att_src, const float* __restrict__ att_dst,
    float* __restrict__ gfeat, float* __restrict__ a_s, float* __restrict__ a_d)
{
    __shared__ float h2T[HID][16];      // [k][b] 16KB
    __shared__ float h3s[NB][HID+1];    // [b][c] 16.4KB
    int t = threadIdx.x;
    int n = blockIdx.x;
    for (int idx = t; idx < NB*HID; idx += 256) {
        int b = idx & 15, k = idx >> 4;
        h2T[k][b] = h2[b*HID + k];
    }
    __syncthreads();
    // Phase A: h3 col (n*256+t) for all 16 batches; 8 loads in flight
    float acc[NB];
    #pragma unroll
    for (int b = 0; b < NB; ++b) acc[b] = 0.f;
    const float* w2p = W2 + (size_t)n*HID + t;
    for (int k0 = 0; k0 < HID; k0 += 8) {
        float wv[8];
        #pragma unroll
        for (int u = 0; u < 8; ++u) wv[u] = w2p[(size_t)(k0+u)*65536];
        #pragma unroll
        for (int u = 0; u < 8; ++u) {
            const float* hr = &h2T[k0+u][0];
            #pragma unroll
            for (int b = 0; b < NB; ++b) acc[b] = fmaf(hr[b], wv[u], acc[b]);
        }
    }
    float bv = b2[n*HID + t];
    #pragma unroll
    for (int b = 0; b < NB; ++b) h3s[b][t] = acc[b] + bv;
    __syncthreads();
    // Phase B: gfeat[b, n, :] = h3s[b] @ Wg ; wave w -> batches w*4..w*4+3
    int l = t & 63, w = t >> 6, cb = l*4;
    float4 g[4];
    #pragma unroll
    for (int rr = 0; rr < 4; ++rr) g[rr] = make_float4(0.f,0.f,0.f,0.f);
    #pragma unroll 4
    for (int k = 0; k < HID; ++k) {
        float4 wg = *(const float4*)&Wg[k*HID + cb];
        #pragma unroll
        for (int rr = 0; rr < 4; ++rr) {
            float hv = h3s[w*4+rr][k];
            g[rr].x = fmaf(hv, wg.x, g[rr].x);
            g[rr].y = fmaf(hv, wg.y, g[rr].y);
            g[rr].z = fmaf(hv, wg.z, g[rr].z);
            g[rr].w = fmaf(hv, wg.w, g[rr].w);
        }
    }
    float4 s4 = *(const float4*)&att_src[cb];
    float4 d4 = *(const float4*)&att_dst[cb];
    int h = l >> 4;
    #pragma unroll
    for (int rr = 0; rr < 4; ++rr) {
        int b = w*4 + rr;
        *(float4*)&gfeat[b*(NN*HID) + n*HID + cb] = g[rr];
        float ps = g[rr].x*s4.x + g[rr].y*s4.y + g[rr].z*s4.z + g[rr].w*s4.w;
        float pd = g[rr].x*d4.x + g[rr].y*d4.y + g[rr].z*d4.z + g[rr].w*d4.w;
        #pragma unroll
        for (int off = 1; off < 16; off <<= 1) {
            ps += __shfl_xor(ps, off);
            pd += __shfl_xor(pd, off);
        }
        if ((l & 15) == 0) {
            a_s[b*(NN*NH) + n*NH + h] = ps;
            a_d[b*(NN*NH) + n*NH + h] = pd;
        }
    }
}

// ---------------- K3: inclusive prefix max of a_s over node index --------------
__global__ __launch_bounds__(64) void k_prefmax(const float* __restrict__ a_s,
    float* __restrict__ prefM)
{
    int bh = blockIdx.x; int b = bh >> 2, h = bh & 3;
    int l = threadIdx.x;
    float carry = -INFINITY;
    for (int ch = 0; ch < 4; ++ch) {
        int n = ch*64 + l;
        float v = a_s[b*(NN*NH) + n*NH + h];
        #pragma unroll
        for (int off = 1; off < 64; off <<= 1) {
            float u = __shfl_up(v, off);
            if (l >= off) v = fmaxf(v, u);
        }
        v = fmaxf(v, carry);
        prefM[b*(NN*NH) + n*NH + h] = v;
        carry = __shfl(v, 63);
    }
}

// ---------------- K4: fused segment-softmax + aggregate + elu + logits +
//                  gumbel argmax. Writes per-row argmax index only. ------------
__global__ __launch_bounds__(256) void k_gatlog(
    const float* __restrict__ gfeat, const float* __restrict__ a_s,
    const float* __restrict__ a_d, const float* __restrict__ prefM,
    const float* __restrict__ bg, const float* __restrict__ Wl,
    const float* __restrict__ bl, const float* __restrict__ gumbel,
    int* __restrict__ biOut)
{
    // pa(h,i,jj) with per-head pad of 4 floats to dodge 4-way bank aliasing
    __shared__ float pa[4*2052];            // 32.8KB, stride 2052 per head
    __shared__ float part[4*JT*256];        // [w|jj|ch] 32KB; reused as partLg
    __shared__ float houtsT[NN][8];         // [k][jj] 8KB
    __shared__ float wsum[4][32];
    __shared__ float redv[4][JT];
    __shared__ int   redi[4][JT];

    int t = threadIdx.x;
    int bb = blockIdx.y;
    int j0 = blockIdx.x * JT;
    int l = t & 63, w = t >> 6;

    // ---- Phase A: p_ij = exp(e - m) for i = t, all 8 j's, 4 heads ----
    float4 as4 = *(const float4*)&a_s[bb*(NN*NH) + t*NH];
    float p[JT][4];
    #pragma unroll
    for (int jj = 0; jj < JT; ++jj) {
        int j = j0 + jj;
        float4 ad4 = *(const float4*)&a_d[bb*(NN*NH) + j*NH];
        float4 pm4 = *(const float4*)&prefM[bb*(NN*NH) + j*NH];
        bool valid = (t <= j);
        p[jj][0] = valid ? expf(lrelu02(as4.x+ad4.x) - lrelu02(pm4.x+ad4.x)) : 0.f;
        p[jj][1] = valid ? expf(lrelu02(as4.y+ad4.y) - lrelu02(pm4.y+ad4.y)) : 0.f;
        p[jj][2] = valid ? expf(lrelu02(as4.z+ad4.z) - lrelu02(pm4.z+ad4.z)) : 0.f;
        p[jj][3] = valid ? expf(lrelu02(as4.w+ad4.w) - lrelu02(pm4.w+ad4.w)) : 0.f;
    }
    #pragma unroll
    for (int jj = 0; jj < JT; ++jj)
        #pragma unroll
        for (int h = 0; h < 4; ++h) {
            float s = p[jj][h];
            #pragma unroll
            for (int off = 1; off < 64; off <<= 1) s += __shfl_xor(s, off);
            if (l == 0) wsum[w][jj*4+h] = s;
        }
    __syncthreads();
    #pragma unroll
    for (int jj = 0; jj < JT; ++jj)
        #pragma unroll
        for (int h = 0; h < 4; ++h) {
            int c = jj*4+h;
            float denom = wsum[0][c] + wsum[1][c] + wsum[2][c] + wsum[3][c];
            pa[h*2052 + t*8 + jj] = p[jj][h] / denom;
        }
    __syncthreads();

    // ---- Phase B: aggregate. lane group q = head, 4 channels/lane (float4) ----
    int q = l >> 4, c4 = (l & 15)*4;         // channel block q*64+c4
    float4 aj[JT];
    #pragma unroll
    for (int jj = 0; jj < JT; ++jj) aj[jj] = make_float4(0.f,0.f,0.f,0.f);
    const float* gb = gfeat + bb*(NN*HID);
    for (int ii = 0; ii < 64; ++ii) {
        int ig = w*64 + ii;
        float4 g4 = *(const float4*)&gb[ig*HID + q*64 + c4];
        float4 pv0 = *(const float4*)&pa[q*2052 + ig*8];
        float4 pv1 = *(const float4*)&pa[q*2052 + ig*8 + 4];
        aj[0].x = fmaf(pv0.x, g4.x, aj[0].x); aj[0].y = fmaf(pv0.x, g4.y, aj[0].y);
        aj[0].z = fmaf(pv0.x, g4.z, aj[0].z); aj[0].w = fmaf(pv0.x, g4.w, aj[0].w);
        aj[1].x = fmaf(pv0.y, g4.x, aj[1].x); aj[1].y = fmaf(pv0.y, g4.y, aj[1].y);
        aj[1].z = fmaf(pv0.y, g4.z, aj[1].z); aj[1].w = fmaf(pv0.y, g4.w, aj[1].w);
        aj[2].x = fmaf(pv0.z, g4.x, aj[2].x); aj[2].y = fmaf(pv0.z, g4.y, aj[2].y);
        aj[2].z = fmaf(pv0.z, g4.z, aj[2].z); aj[2].w = fmaf(pv0.z, g4.w, aj[2].w);
        aj[3].x = fmaf(pv0.w, g4.x, aj[3].x); aj[3].y = fmaf(pv0.w, g4.y, aj[3].y);
        aj[3].z = fmaf(pv0.w, g4.z, aj[3].z); aj[3].w = fmaf(pv0.w, g4.w, aj[3].w);
        aj[4].x = fmaf(pv1.x, g4.x, aj[4].x); aj[4].y = fmaf(pv1.x, g4.y, aj[4].y);
        aj[4].z = fmaf(pv1.x, g4.z, aj[4].z); aj[4].w = fmaf(pv1.x, g4.w, aj[4].w);
        aj[5].x = fmaf(pv1.y, g4.x, aj[5].x); aj[5].y = fmaf(pv1.y, g4.y, aj[5].y);
        aj[5].z = fmaf(pv1.y, g4.z, aj[5].z); aj[5].w = fmaf(pv1.y, g4.w, aj[5].w);
        aj[6].x = fmaf(pv1.z, g4.x, aj[6].x); aj[6].y = fmaf(pv1.z, g4.y, aj[6].y);
        aj[6].z = fmaf(pv1.z, g4.z, aj[6].z); aj[6].w = fmaf(pv1.z, g4.w, aj[6].w);
        aj[7].x = fmaf(pv1.w, g4.x, aj[7].x); aj[7].y = fmaf(pv1.w, g4.y, aj[7].y);
        aj[7].z = fmaf(pv1.w, g4.z, aj[7].z); aj[7].w = fmaf(pv1.w, g4.w, aj[7].w);
    }
    #pragma unroll
    for (int jj = 0; jj < JT; ++jj)
        *(float4*)&part[(w*JT + jj)*256 + q*64 + c4] = aj[jj];
    __syncthreads();

    // ---- Phase C: combine waves, +bg, elu -> houtsT[k][jj] ----
    {
        float bgv = bg[t];
        #pragma unroll
        for (int jj = 0; jj < JT; ++jj) {
            float s = part[(0*JT+jj)*256 + t] + part[(1*JT+jj)*256 + t]
                    + part[(2*JT+jj)*256 + t] + part[(3*JT+jj)*256 + t] + bgv;
            houtsT[t][jj] = eluf(s);
        }
    }
    __syncthreads();

    // ---- Phase D: logits: wave w covers k in [64w,64w+64); thread = 4 cols ----
    int cb = l*4;
    float4 lg[JT];
    #pragma unroll
    for (int jj = 0; jj < JT; ++jj) lg[jj] = make_float4(0.f,0.f,0.f,0.f);
    for (int kk = 0; kk < 64; ++kk) {
        int k = w*64 + kk;
        float4 hA = *(const float4*)&houtsT[k][0];
        float4 hB = *(const float4*)&houtsT[k][4];
        float4 wl4 = *(const float4*)&Wl[k*HID + cb];
        lg[0].x = fmaf(hA.x, wl4.x, lg[0].x); lg[0].y = fmaf(hA.x, wl4.y, lg[0].y);
        lg[0].z = fmaf(hA.x, wl4.z, lg[0].z); lg[0].w = fmaf(hA.x, wl4.w, lg[0].w);
        lg[1].x = fmaf(hA.y, wl4.x, lg[1].x); lg[1].y = fmaf(hA.y, wl4.y, lg[1].y);
        lg[1].z = fmaf(hA.y, wl4.z, lg[1].z); lg[1].w = fmaf(hA.y, wl4.w, lg[1].w);
        lg[2].x = fmaf(hA.z, wl4.x, lg[2].x); lg[2].y = fmaf(hA.z, wl4.y, lg[2].y);
        lg[2].z = fmaf(hA.z, wl4.z, lg[2].z); lg[2].w = fmaf(hA.z, wl4.w, lg[2].w);
        lg[3].x = fmaf(hA.w, wl4.x, lg[3].x); lg[3].y = fmaf(hA.w, wl4.y, lg[3].y);
        lg[3].z = fmaf(hA.w, wl4.z, lg[3].z); lg[3].w = fmaf(hA.w, wl4.w, lg[3].w);
        lg[4].x = fmaf(hB.x, wl4.x, lg[4].x); lg[4].y = fmaf(hB.x, wl4.y, lg[4].y);
        lg[4].z = fmaf(hB.x, wl4.z, lg[4].z); lg[4].w = fmaf(hB.x, wl4.w, lg[4].w);
        lg[5].x = fmaf(hB.y, wl4.x, lg[5].x); lg[5].y = fmaf(hB.y, wl4.y, lg[5].y);
        lg[5].z = fmaf(hB.y, wl4.z, lg[5].z); lg[5].w = fmaf(hB.y, wl4.w, lg[5].w);
        lg[6].x = fmaf(hB.z, wl4.x, lg[6].x); lg[6].y = fmaf(hB.z, wl4.y, lg[6].y);
        lg[6].z = fmaf(hB.z, wl4.z, lg[6].z); lg[6].w = fmaf(hB.z, wl4.w, lg[6].w);
        lg[7].x = fmaf(hB.w, wl4.x, lg[7].x); lg[7].y = fmaf(hB.w, wl4.y, lg[7].y);
        lg[7].z = fmaf(hB.w, wl4.z, lg[7].z); lg[7].w = fmaf(hB.w, wl4.w, lg[7].w);
    }
    __syncthreads();    // part's phase-B/C data fully consumed; reuse as partLg
    #pragma unroll
    for (int jj = 0; jj < JT; ++jj)
        *(float4*)&part[(w*JT + jj)*256 + cb] = lg[jj];
    __syncthreads();

    // ---- Final: z = logits + bl + gumbel; per-row argmax -> biOut ----
    {
        float blv = bl[t];
        #pragma unroll
        for (int jj = 0; jj < JT; ++jj) {
            float z = part[(0*JT+jj)*256 + t] + part[(1*JT+jj)*256 + t]
                    + part[(2*JT+jj)*256 + t] + part[(3*JT+jj)*256 + t]
                    + blv + gumbel[bb*(NN*NN) + (j0+jj)*NN + t];
            float bv = z; int bi_ = t;
            #pragma unroll
            for (int off = 1; off < 64; off <<= 1) {
                float ov = __shfl_xor(bv, off);
                int   oi = __shfl_xor(bi_, off);
                if (ov > bv || (ov == bv && oi < bi_)) { bv = ov; bi_ = oi; }
            }
            if (l == 0) { redv[w][jj] = bv; redi[w][jj] = bi_; }
        }
    }
    __syncthreads();
    if (t < JT) {
        float bv = redv[0][t]; int bi_ = redi[0][t];
        #pragma unroll
        for (int ww = 1; ww < 4; ++ww)
            if (redv[ww][t] > bv) { bv = redv[ww][t]; bi_ = redi[ww][t]; }
        biOut[bb*NN + j0 + t] = bi_;
    }
}

// ---------------- K5: zero adj slice + symmetric one-hot scatter ---------------
__global__ __launch_bounds__(256) void k_adj(const int* __restrict__ bi,
    float* __restrict__ adj)
{
    int bb = blockIdx.x, t = threadIdx.x;
    float4* ap = (float4*)(adj + (size_t)bb*(NN*NN));
    float4 z = make_float4(0.f,0.f,0.f,0.f);
    for (int idx = t; idx < NN*NN/4; idx += 256) ap[idx] = z;
    __syncthreads();
    int b = bi[bb*NN + t];
    adj[(size_t)bb*(NN*NN) + t*NN + b] = 1.0f;
    adj[(size_t)bb*(NN*NN) + b*NN + t] = 1.0f;
}

extern "C" void kernel_launch(void* const* d_in, const int* in_sizes, int n_in,
                              void* d_out, int out_size, void* d_ws, size_t ws_size,
                              hipStream_t stream)
{
    const float* x       = (const float*)d_in[0];
    const float* W0      = (const float*)d_in[1];
    const float* b0      = (const float*)d_in[2];
    const float* W1      = (const float*)d_in[3];
    const float* b1      = (const float*)d_in[4];
    const float* W2      = (const float*)d_in[5];
    const float* b2      = (const float*)d_in[6];
    const float* Wg      = (const float*)d_in[7];
    const float* att_src = (const float*)d_in[8];
    const float* att_dst = (const float*)d_in[9];
    const float* bg      = (const float*)d_in[10];
    const float* Wl      = (const float*)d_in[11];
    const float* bl      = (const float*)d_in[12];
    const float* gumbel  = (const float*)d_in[13];

    // ws footprint: 57,344 floats = 229 KB total (no 4MB intermediates).
    float* ws    = (float*)d_ws;
    float* h2    = ws;                  // 4096
    float* a_s   = h2 + 4096;           // 16384
    float* a_d   = a_s + 16384;         // 16384
    float* prefM = a_d + 16384;         // 16384
    int*   biIdx = (int*)(prefM + 16384); // 4096 ints
    float* gfeat = (float*)d_out;       // d_out doubles as gfeat scratch (4MB)
    float* adj   = (float*)d_out;

    k_mlp12 <<<NB, 256, 0, stream>>>(x, W0, b0, W1, b1, h2);
    k_mlp3g <<<NN, 256, 0, stream>>>(h2, W2, b2, Wg, att_src, att_dst, gfeat, a_s, a_d);
    k_prefmax<<<NB*NH, 64, 0, stream>>>(a_s, prefM);
    k_gatlog<<<dim3(NN/JT, NB), 256, 0, stream>>>(gfeat, a_s, a_d, prefM, bg, Wl, bl, gumbel, biIdx);
    k_adj   <<<NB, 256, 0, stream>>>(biIdx, adj);
}

// Round 4
// 88.759 us; speedup vs baseline: 1.1695x; 1.1695x over previous
//
#include <hip/hip_runtime.h>
#include <math.h>

#define NB 16      // batch
#define LAT 128
#define HID 256
#define NN 256     // nodes
#define NH 4       // heads
#define JT 4       // dst-tile per gat block

__device__ __forceinline__ float lrelu02(float x){ return x > 0.f ? x : 0.2f*x; }
__device__ __forceinline__ float eluf(float x){ return x > 0.f ? x : expm1f(x); }

// ---------------- K1: h2 = relu(relu(x@W0+b0)@W1+b1)  [16,256] ----------------
__global__ __launch_bounds__(256) void k_mlp12(const float* __restrict__ x,
    const float* __restrict__ W0, const float* __restrict__ b0,
    const float* __restrict__ W1, const float* __restrict__ b1,
    float* __restrict__ h2)
{
    __shared__ float xs[LAT];
    __shared__ float h1s[HID];
    int b = blockIdx.x, t = threadIdx.x;
    if (t < LAT) xs[t] = x[b*LAT + t];
    __syncthreads();
    float acc = b0[t];
    for (int k = 0; k < LAT; ++k) acc = fmaf(xs[k], W0[k*HID + t], acc);
    h1s[t] = fmaxf(acc, 0.f);
    __syncthreads();
    float acc2 = b1[t];
    for (int k = 0; k < HID; ++k) acc2 = fmaf(h1s[k], W1[k*HID + t], acc2);
    h2[b*HID + t] = fmaxf(acc2, 0.f);
}

// ---------------- K2: fused h3 = h2@W2+b2 then gfeat = h3@Wg, a_s/a_d ----------
// 512 threads: k-range split in two halves for 2x memory parallelism on W2.
__global__ __launch_bounds__(512) void k_mlp3g(
    const float* __restrict__ h2, const float* __restrict__ W2,
    const float* __restrict__ b2, const float* __restrict__ Wg,
    const float* __restrict__ att_src, const float* __restrict__ att_dst,
    float* __restrict__ gfeat, float* __restrict__ a_s, float* __restrict__ a_d)
{
    __shared__ float h2T[HID][16];      // [k][b] 16KB
    __shared__ float red[256*17];       // k-half partial sums, padded 17KB
    __shared__ float h3s[NB][HID+1];    // [b][c] 16.4KB
    int t = threadIdx.x;
    int n = blockIdx.x;
    int col = t & 255, kh = t >> 8;
    for (int idx = t; idx < NB*HID; idx += 512) {
        int b = idx & 15, k = idx >> 4;
        h2T[k][b] = h2[b*HID + k];
    }
    __syncthreads();
    float acc[NB];
    #pragma unroll
    for (int b = 0; b < NB; ++b) acc[b] = 0.f;
    const float* w2p = W2 + (size_t)kh*128*65536 + (size_t)n*HID + col;
    for (int k0 = 0; k0 < 128; k0 += 16) {
        float wv[16];
        #pragma unroll
        for (int u = 0; u < 16; ++u) wv[u] = w2p[(size_t)(k0+u)*65536];
        #pragma unroll
        for (int u = 0; u < 16; ++u) {
            const float* hr = &h2T[kh*128 + k0 + u][0];
            #pragma unroll
            for (int b = 0; b < NB; ++b) acc[b] = fmaf(hr[b], wv[u], acc[b]);
        }
    }
    if (kh == 1) {
        #pragma unroll
        for (int b = 0; b < NB; ++b) red[col*17 + b] = acc[b];
    }
    __syncthreads();
    if (kh == 0) {
        float bv = b2[n*HID + col];
        #pragma unroll
        for (int b = 0; b < NB; ++b) h3s[b][col] = acc[b] + red[col*17 + b] + bv;
    }
    __syncthreads();
    // Phase B: 8 waves; wave w handles batches 2w, 2w+1
    int l = t & 63, w = t >> 6, cb = l*4;
    float4 g[2];
    g[0] = make_float4(0.f,0.f,0.f,0.f); g[1] = g[0];
    #pragma unroll 4
    for (int k = 0; k < HID; ++k) {
        float4 wg = *(const float4*)&Wg[k*HID + cb];
        #pragma unroll
        for (int rr = 0; rr < 2; ++rr) {
            float hv = h3s[w*2+rr][k];
            g[rr].x = fmaf(hv, wg.x, g[rr].x);
            g[rr].y = fmaf(hv, wg.y, g[rr].y);
            g[rr].z = fmaf(hv, wg.z, g[rr].z);
            g[rr].w = fmaf(hv, wg.w, g[rr].w);
        }
    }
    float4 s4 = *(const float4*)&att_src[cb];
    float4 d4 = *(const float4*)&att_dst[cb];
    int h = l >> 4;
    #pragma unroll
    for (int rr = 0; rr < 2; ++rr) {
        int b = w*2 + rr;
        *(float4*)&gfeat[b*(NN*HID) + n*HID + cb] = g[rr];
        float ps = g[rr].x*s4.x + g[rr].y*s4.y + g[rr].z*s4.z + g[rr].w*s4.w;
        float pd = g[rr].x*d4.x + g[rr].y*d4.y + g[rr].z*d4.z + g[rr].w*d4.w;
        #pragma unroll
        for (int off = 1; off < 16; off <<= 1) {
            ps += __shfl_xor(ps, off);
            pd += __shfl_xor(pd, off);
        }
        if ((l & 15) == 0) {
            a_s[b*(NN*NH) + n*NH + h] = ps;
            a_d[b*(NN*NH) + n*NH + h] = pd;
        }
    }
}

// ---------------- K3: per (b,h,j): S_j = exp(-m_j)/den_j  (single buffer) ------
// grid 256 = (b, h, jchunk); 4 lanes cooperate per j.
__global__ __launch_bounds__(256) void k_prefden(const float* __restrict__ a_s,
    const float* __restrict__ a_d, float* __restrict__ sArr)
{
    __shared__ float as_sh[NN];
    int id = blockIdx.x;
    int b = id >> 4, h = (id >> 2) & 3, jc = id & 3;
    int t = threadIdx.x;
    as_sh[t] = a_s[b*(NN*NH) + t*NH + h];
    __syncthreads();
    int jl = t >> 2, r = t & 3;
    int j = jc*64 + jl;
    float ad = a_d[b*(NN*NH) + j*NH + h];
    // pass 1: max over i <= j (4-lane split)
    float lm = -INFINITY;
    for (int i = r; i <= j; i += 4) lm = fmaxf(lm, as_sh[i]);
    lm = fmaxf(lm, __shfl_xor(lm, 1));
    lm = fmaxf(lm, __shfl_xor(lm, 2));
    float m = lrelu02(lm + ad);
    // pass 2: denom of exp(e - m)
    float s = 0.f;
    for (int i = r; i <= j; i += 4) s += expf(lrelu02(as_sh[i] + ad) - m);
    s += __shfl_xor(s, 1);
    s += __shfl_xor(s, 2);
    if (r == 0) {
        // alpha_ij = exp(e_ij) * S_j ; scores are O(0.3) so exp() is safe
        sArr[b*(NN*NH) + j*NH + h] = expf(-m) / s;
    }
}

// ---------------- K4: fused alpha + aggregate + elu + logits + argmax ----------
__global__ __launch_bounds__(256) void k_gatlog(
    const float* __restrict__ gfeat, const float* __restrict__ a_s,
    const float* __restrict__ a_d, const float* __restrict__ sArr,
    const float* __restrict__ bg, const float* __restrict__ Wl,
    const float* __restrict__ bl, const float* __restrict__ gumbel,
    int* __restrict__ biOut)
{
    __shared__ float pa[4*1032];        // [h][i][jj], 1032-stride pad  16.5KB
    __shared__ float part[16*256];      // [w|jj][c]                    16KB
    __shared__ float houts[NN*4];       // [k][jj]                      4KB
    __shared__ float redv[4][JT];
    __shared__ int   redi[4][JT];

    int t = threadIdx.x;
    // XCD swizzle: block i lands on XCD i%8; give each XCD 2 whole batches.
    int id = blockIdx.x;
    int xcd = id & 7, k2 = id >> 3;
    int bb = (xcd << 1) | (k2 >> 6);
    int j0 = (k2 & 63) * JT;
    int l = t & 63, w = t >> 6;

    // ---- Phase A: alpha(i=t, j0..j0+3, all h) -> pa ----
    float pr[JT][4];
    if (w*64 <= j0 + JT - 1) {
        float4 as4 = *(const float4*)&a_s[bb*(NN*NH) + t*NH];
        #pragma unroll
        for (int jj = 0; jj < JT; ++jj) {
            int j = j0 + jj;
            float4 ad4 = *(const float4*)&a_d[bb*(NN*NH) + j*NH];
            float4 sv4 = *(const float4*)&sArr[bb*(NN*NH) + j*NH];
            bool valid = (t <= j);
            pr[jj][0] = valid ? expf(lrelu02(as4.x+ad4.x)) * sv4.x : 0.f;
            pr[jj][1] = valid ? expf(lrelu02(as4.y+ad4.y)) * sv4.y : 0.f;
            pr[jj][2] = valid ? expf(lrelu02(as4.z+ad4.z)) * sv4.z : 0.f;
            pr[jj][3] = valid ? expf(lrelu02(as4.w+ad4.w)) * sv4.w : 0.f;
        }
    } else {
        #pragma unroll
        for (int jj = 0; jj < JT; ++jj)
            #pragma unroll
            for (int h = 0; h < 4; ++h) pr[jj][h] = 0.f;
    }
    #pragma unroll
    for (int h = 0; h < 4; ++h)
        *(float4*)&pa[h*1032 + t*4] = make_float4(pr[0][h], pr[1][h], pr[2][h], pr[3][h]);
    __syncthreads();

    // ---- Phase B: aggregate over i <= j0+3 only (alpha is 0 above diagonal) ----
    int q = l >> 4, c4 = (l & 15) * 4;        // channel q*64+c4
    float4 aj[JT];
    #pragma unroll
    for (int jj = 0; jj < JT; ++jj) aj[jj] = make_float4(0.f,0.f,0.f,0.f);
    const float* gb = gfeat + bb*(NN*HID);
    int lim = j0 + JT - w*64; lim = lim < 0 ? 0 : (lim > 64 ? 64 : lim);
    #pragma unroll 4
    for (int ii = 0; ii < lim; ++ii) {
        int ig = w*64 + ii;
        float4 g4 = *(const float4*)&gb[ig*HID + q*64 + c4];
        float4 pv = *(const float4*)&pa[q*1032 + ig*4];
        aj[0].x = fmaf(pv.x, g4.x, aj[0].x); aj[0].y = fmaf(pv.x, g4.y, aj[0].y);
        aj[0].z = fmaf(pv.x, g4.z, aj[0].z); aj[0].w = fmaf(pv.x, g4.w, aj[0].w);
        aj[1].x = fmaf(pv.y, g4.x, aj[1].x); aj[1].y = fmaf(pv.y, g4.y, aj[1].y);
        aj[1].z = fmaf(pv.y, g4.z, aj[1].z); aj[1].w = fmaf(pv.y, g4.w, aj[1].w);
        aj[2].x = fmaf(pv.z, g4.x, aj[2].x); aj[2].y = fmaf(pv.z, g4.y, aj[2].y);
        aj[2].z = fmaf(pv.z, g4.z, aj[2].z); aj[2].w = fmaf(pv.z, g4.w, aj[2].w);
        aj[3].x = fmaf(pv.w, g4.x, aj[3].x); aj[3].y = fmaf(pv.w, g4.y, aj[3].y);
        aj[3].z = fmaf(pv.w, g4.z, aj[3].z); aj[3].w = fmaf(pv.w, g4.w, aj[3].w);
    }
    #pragma unroll
    for (int jj = 0; jj < JT; ++jj)
        *(float4*)&part[(w*JT + jj)*256 + q*64 + c4] = aj[jj];
    __syncthreads();

    // ---- Phase C: combine waves, +bg, elu -> houts[k][jj] ----
    {
        float bgv = bg[t];
        float hh[JT];
        #pragma unroll
        for (int jj = 0; jj < JT; ++jj) {
            float s = part[(0*JT+jj)*256 + t] + part[(1*JT+jj)*256 + t]
                    + part[(2*JT+jj)*256 + t] + part[(3*JT+jj)*256 + t] + bgv;
            hh[jj] = eluf(s);
        }
        *(float4*)&houts[t*4] = make_float4(hh[0], hh[1], hh[2], hh[3]);
    }
    __syncthreads();

    // ---- Phase D: partial logits over k in [64w, 64w+64) ----
    int cb = l*4;
    float4 lg[JT];
    #pragma unroll
    for (int jj = 0; jj < JT; ++jj) lg[jj] = make_float4(0.f,0.f,0.f,0.f);
    #pragma unroll 2
    for (int kk = 0; kk < 64; ++kk) {
        int k = w*64 + kk;
        float4 hv  = *(const float4*)&houts[k*4];
        float4 wl4 = *(const float4*)&Wl[k*HID + cb];
        lg[0].x = fmaf(hv.x, wl4.x, lg[0].x); lg[0].y = fmaf(hv.x, wl4.y, lg[0].y);
        lg[0].z = fmaf(hv.x, wl4.z, lg[0].z); lg[0].w = fmaf(hv.x, wl4.w, lg[0].w);
        lg[1].x = fmaf(hv.y, wl4.x, lg[1].x); lg[1].y = fmaf(hv.y, wl4.y, lg[1].y);
        lg[1].z = fmaf(hv.y, wl4.z, lg[1].z); lg[1].w = fmaf(hv.y, wl4.w, lg[1].w);
        lg[2].x = fmaf(hv.z, wl4.x, lg[2].x); lg[2].y = fmaf(hv.z, wl4.y, lg[2].y);
        lg[2].z = fmaf(hv.z, wl4.z, lg[2].z); lg[2].w = fmaf(hv.z, wl4.w, lg[2].w);
        lg[3].x = fmaf(hv.w, wl4.x, lg[3].x); lg[3].y = fmaf(hv.w, wl4.y, lg[3].y);
        lg[3].z = fmaf(hv.w, wl4.z, lg[3].z); lg[3].w = fmaf(hv.w, wl4.w, lg[3].w);
    }
    #pragma unroll
    for (int jj = 0; jj < JT; ++jj)
        *(float4*)&part[(w*JT + jj)*256 + cb] = lg[jj];
    __syncthreads();

    // ---- Final: z = logits + bl + gumbel; per-row argmax ----
    float blv = bl[t];
    #pragma unroll
    for (int jj = 0; jj < JT; ++jj) {
        float z = part[(0*JT+jj)*256 + t] + part[(1*JT+jj)*256 + t]
                + part[(2*JT+jj)*256 + t] + part[(3*JT+jj)*256 + t]
                + blv + gumbel[bb*(NN*NN) + (j0+jj)*NN + t];
        float bv = z; int bi_ = t;
        #pragma unroll
        for (int off = 1; off < 64; off <<= 1) {
            float ov = __shfl_xor(bv, off);
            int   oi = __shfl_xor(bi_, off);
            if (ov > bv || (ov == bv && oi < bi_)) { bv = ov; bi_ = oi; }
        }
        if (l == 0) { redv[w][jj] = bv; redi[w][jj] = bi_; }
    }
    __syncthreads();
    if (t < JT) {
        float bv = redv[0][t]; int bi_ = redi[0][t];
        #pragma unroll
        for (int ww = 1; ww < 4; ++ww)
            if (redv[ww][t] > bv) { bv = redv[ww][t]; bi_ = redi[ww][t]; }
        biOut[bb*NN + j0 + t] = bi_;
    }
}

// ---------------- K5: zero adj slice + symmetric one-hot scatter ---------------
__global__ __launch_bounds__(256) void k_adj(const int* __restrict__ bi,
    float* __restrict__ adj)
{
    int bb = blockIdx.x, t = threadIdx.x;
    float4* ap = (float4*)(adj + (size_t)bb*(NN*NN));
    float4 z = make_float4(0.f,0.f,0.f,0.f);
    for (int idx = t; idx < NN*NN/4; idx += 256) ap[idx] = z;
    __syncthreads();
    int b = bi[bb*NN + t];
    adj[(size_t)bb*(NN*NN) + t*NN + b] = 1.0f;
    adj[(size_t)bb*(NN*NN) + b*NN + t] = 1.0f;
}

extern "C" void kernel_launch(void* const* d_in, const int* in_sizes, int n_in,
                              void* d_out, int out_size, void* d_ws, size_t ws_size,
                              hipStream_t stream)
{
    const float* x       = (const float*)d_in[0];
    const float* W0      = (const float*)d_in[1];
    const float* b0      = (const float*)d_in[2];
    const float* W1      = (const float*)d_in[3];
    const float* b1      = (const float*)d_in[4];
    const float* W2      = (const float*)d_in[5];
    const float* b2      = (const float*)d_in[6];
    const float* Wg      = (const float*)d_in[7];
    const float* att_src = (const float*)d_in[8];
    const float* att_dst = (const float*)d_in[9];
    const float* bg      = (const float*)d_in[10];
    const float* Wl      = (const float*)d_in[11];
    const float* bl      = (const float*)d_in[12];
    const float* gumbel  = (const float*)d_in[13];

    // ws footprint: 57,344 floats = 229 KB (same as the passing Round-2 layout;
    // ws_size appears to be 256 KB — NEVER exceed it).
    float* ws     = (float*)d_ws;
    float* h2     = ws;                    // 4096
    float* a_s    = h2 + 4096;             // 16384
    float* a_d    = a_s + 16384;           // 16384
    float* sArr   = a_d + 16384;           // 16384
    int*   biIdx  = (int*)(sArr + 16384);  // 4096 ints
    float* gfeat  = (float*)d_out;         // d_out doubles as gfeat scratch (4MB)
    float* adj    = (float*)d_out;

    k_mlp12  <<<NB, 256, 0, stream>>>(x, W0, b0, W1, b1, h2);
    k_mlp3g  <<<NN, 512, 0, stream>>>(h2, W2, b2, Wg, att_src, att_dst, gfeat, a_s, a_d);
    k_prefden<<<256, 256, 0, stream>>>(a_s, a_d, sArr);
    k_gatlog <<<NB*64, 256, 0, stream>>>(gfeat, a_s, a_d, sArr, bg, Wl, bl, gumbel, biIdx);
    k_adj    <<<NB, 256, 0, stream>>>(biIdx, adj);
}